// Round 7
// baseline (280.753 us; speedup 1.0000x reference)
//
#include <hip/hip_runtime.h>
#include <math.h>

// Problem constants (B=1)
#define NTOK 4096
#define EMB  256
#define NH   4
#define HD   64

typedef unsigned short u16;
typedef __attribute__((ext_vector_type(8))) __bf16 bf16x8;
typedef __attribute__((ext_vector_type(4))) float f32x4;

__device__ __forceinline__ u16 f2bf(float f) {
    union { float f; unsigned u; } v; v.f = f;
    unsigned b = v.u;
    b += 0x7FFFu + ((b >> 16) & 1u);     // round-nearest-even
    return (u16)(b >> 16);
}
__device__ __forceinline__ float bf2f(u16 u) {
    union { unsigned u; float f; } v; v.u = ((unsigned)u) << 16;
    return v.f;
}

// ---------------------------------------------------------------------------
// prep = w4cast + xcast fused (grid-partitioned).
// blocks [0,640): 4 fp32 weight tensors -> concat bf16 wb.
// blocks [640,1664): x fp32 -> xb bf16 AND catb[:, :256] (row stride 512).
// ---------------------------------------------------------------------------
__global__ __launch_bounds__(256) void prep(
    const float4* __restrict__ w0, const float4* __restrict__ w1,
    const float4* __restrict__ w2, const float4* __restrict__ w3,
    u16* __restrict__ wb,
    const float4* __restrict__ x4, u16* __restrict__ xb, u16* __restrict__ catb)
{
    const int bid = blockIdx.x;
    if (bid < 640) {
        const int f = bid * 256 + threadIdx.x;   // < 163840
        float4 v;
        if      (f <  49152) v = w0[f];
        else if (f <  65536) v = w1[f - 49152];
        else if (f < 131072) v = w2[f - 65536];
        else                 v = w3[f - 131072];
        uint2 o;
        o.x = (unsigned)f2bf(v.x) | ((unsigned)f2bf(v.y) << 16);
        o.y = (unsigned)f2bf(v.z) | ((unsigned)f2bf(v.w) << 16);
        *(uint2*)(wb + (size_t)f * 4) = o;
    } else {
        const int f = (bid - 640) * 256 + threadIdx.x;   // < 262144
        float4 v = x4[f];
        uint2 o;
        o.x = (unsigned)f2bf(v.x) | ((unsigned)f2bf(v.y) << 16);
        o.y = (unsigned)f2bf(v.z) | ((unsigned)f2bf(v.w) << 16);
        *(uint2*)(xb + (size_t)f * 4) = o;
        const int row = f >> 6, c = (f & 63) * 4;
        *(uint2*)(catb + (size_t)row * 512 + c) = o;
    }
}

// ---------------------------------------------------------------------------
// bf16 MFMA GEMM: C[m][n] = sum_k A[m][k]*B[n][k] + bias[n] (+resid).
// Block 256 thr / 4 waves; tile 64(M)x64(N); wave w owns rows w*16..+15.
// ---------------------------------------------------------------------------
__global__ __launch_bounds__(256) void gemm_bf16_abt(
    const u16* __restrict__ A,     // [M][K] bf16
    const u16* __restrict__ B,     // [N][K] bf16
    const float* __restrict__ bias,
    const float* __restrict__ resid, int ldr,   // may be null
    float* __restrict__ Cf, u16* __restrict__ Cb, int ldc, int K)
{
    const int t = threadIdx.x, w = t >> 6, l = t & 63;
    const int lg = l >> 4, li = l & 15;
    const int row0 = blockIdx.y * 64 + w * 16;
    const int col0 = blockIdx.x * 64;

    f32x4 acc[4];
    #pragma unroll
    for (int nb = 0; nb < 4; ++nb) acc[nb] = (f32x4){0.f, 0.f, 0.f, 0.f};

    const u16* Ap = A + (size_t)(row0 + li) * K + lg * 8;
    const u16* Bp = B + (size_t)(col0 + li) * K + lg * 8;

    #pragma unroll 2
    for (int k0 = 0; k0 < K; k0 += 32) {
        bf16x8 a = *(const bf16x8*)(Ap + k0);
        #pragma unroll
        for (int nb = 0; nb < 4; ++nb) {
            bf16x8 b = *(const bf16x8*)(Bp + (size_t)nb * 16 * K + k0);
            acc[nb] = __builtin_amdgcn_mfma_f32_16x16x32_bf16(a, b, acc[nb], 0, 0, 0);
        }
    }

    #pragma unroll
    for (int nb = 0; nb < 4; ++nb) {
        const int col = col0 + nb * 16 + li;
        const float bs = bias[col];
        #pragma unroll
        for (int p = 0; p < 4; ++p) {
            const int row = row0 + lg * 4 + p;
            float v = acc[nb][p] + bs;
            if (resid) v += resid[(size_t)row * ldr + col];
            if (Cf) Cf[(size_t)row * ldc + col] = v;
            else    Cb[(size_t)row * ldc + col] = f2bf(v);
        }
    }
}

// ---------------------------------------------------------------------------
// qkv_post = rope_qk + v_transpose (LDS-tiled) fused, grid-partitioned.
// blocks [0,2048): RoPE -> bf16 Q (x0.125) and K, layout [h][n][64].
// blocks [2048,2304): V slot -> bf16 transposed Vt[h][d][key] via LDS tile.
// qkvb row layout per n: h*192 + d*3 + {0:q,1:k,2:v}.
// ---------------------------------------------------------------------------
__global__ __launch_bounds__(256) void qkv_post(
    const u16* __restrict__ qkvb, const float* __restrict__ enc,
    unsigned* __restrict__ Qb, unsigned* __restrict__ Kb, u16* __restrict__ Vt)
{
    __shared__ u16 lds[64 * 66];
    const int bid = blockIdx.x;
    if (bid < 2048) {
        const int gid = bid * 256 + threadIdx.x;   // NH*NTOK*32
        const int h   = gid >> 17;
        const int rem = gid & (NTOK * 32 - 1);
        const int n   = rem >> 5;
        const int p   = rem & 31;
        const int d0  = p * 2;

        const u16* base = qkvb + (size_t)n * 768 + h * 192 + d0 * 3;
        const float q0v = bf2f(base[0]), k0 = bf2f(base[1]);
        const float q1  = bf2f(base[3]), k1 = bf2f(base[4]);

        float2 c01 = *(const float2*)(enc + (size_t)n * 64 + d0);
        float2 s01 = *(const float2*)(enc + (size_t)NTOK * 64 + (size_t)n * 64 + d0);

        const float qo0 = (q0v * c01.x - q1 * s01.x) * 0.125f;
        const float qo1 = (q1 * c01.y + q0v * s01.y) * 0.125f;
        const float ko0 = k0 * c01.x - k1 * s01.x;
        const float ko1 = k1 * c01.y + k0 * s01.y;

        const size_t oidx = ((size_t)(h * NTOK + n) << 5) + p;
        Qb[oidx] = (unsigned)f2bf(qo0) | ((unsigned)f2bf(qo1) << 16);
        Kb[oidx] = (unsigned)f2bf(ko0) | ((unsigned)f2bf(ko1) << 16);
    } else {
        const int vb = bid - 2048;
        const int h  = vb >> 6;
        const int nt = vb & 63;
        const int t  = threadIdx.x;

        // phase 1: read v-slot (reads clustered in 96B per thread), LDS [d][n]
        {
            const int nl = t & 63, dg = t >> 6;   // dg: 0..3 (16 d each)
            const u16* src = qkvb + (size_t)(nt * 64 + nl) * 768 + h * 192 + dg * 48 + 2;
            #pragma unroll
            for (int i = 0; i < 16; ++i)
                lds[(dg * 16 + i) * 66 + nl] = src[3 * i];
        }
        __syncthreads();
        // phase 2: write 128B-per-wave coalesced rows of Vt
        {
            const int d = t >> 2, nc = t & 3;
            __align__(16) u16 us[16];
            #pragma unroll
            for (int i = 0; i < 16; ++i) us[i] = lds[d * 66 + nc * 16 + i];
            u16* dst = Vt + ((size_t)(h * 64 + d) << 12) + nt * 64 + nc * 16;
            *(uint4*)(dst)     = *(uint4*)(us);
            *(uint4*)(dst + 8) = *(uint4*)(us + 8);
        }
    }
}

// ---------------------------------------------------------------------------
// Flash attention v4, bf16 MFMA. q-tile 16 (Mb=1); 4 waves/block (256 thr),
// wave wk owns keys [wk*1024, +1024) over all 16 q-rows. Grid (256 q-tiles,
// 4 heads) = 1024 SMALL blocks -> target 4 blocks/CU = 16 waves/CU.
// Fragments (HW-verified r3/r4): A[row=li][k=lg*8+j], B[col=li][k=lg*8+j],
// D[row=lg*4+p][col=li]. P via per-wave 2KB LDS tile, 16B-slot XOR swizzle.
// lrun lane-partial through main loop; cross-wk merge via LDS (4 phases).
// ---------------------------------------------------------------------------
__global__ __launch_bounds__(256, 4) void flash_attn_v4(
    const u16* __restrict__ Qb, const u16* __restrict__ Kb,
    const u16* __restrict__ Vt, u16* __restrict__ ctxb)
{
    __shared__ char  Plds[4 * 2048];
    __shared__ float Obuf[16 * 64];
    __shared__ float Mbuf[16], Lbuf[16];

    const int t  = threadIdx.x;
    const int wk = t >> 6;              // 0..3: key-quarter
    const int l  = t & 63;
    const int lg = l >> 4, li = l & 15;
    const int h  = blockIdx.y;
    const int q0 = blockIdx.x * 16;

    char* Pw = Plds + wk * 2048;

    // Q fragments: row q0 + li, d = kh*32 + lg*8 + {0..7}
    bf16x8 QA[2];
    #pragma unroll
    for (int kh = 0; kh < 2; ++kh)
        QA[kh] = *(const bf16x8*)(Qb +
            ((size_t)(h * NTOK + q0 + li) << 6) + kh * 32 + lg * 8);

    f32x4 OA[4];                 // [db]
    float mrun[4], lrun[4];      // [p]; lrun lane-partial until the end
    #pragma unroll
    for (int p = 0; p < 4; ++p) { mrun[p] = -1e30f; lrun[p] = 0.f; }
    #pragma unroll
    for (int db = 0; db < 4; ++db) OA[db] = (f32x4){0.f, 0.f, 0.f, 0.f};

    for (int it = 0; it < 16; ++it) {
        const int kt = (wk << 10) + (it << 6);

        bf16x8 KB[4][2], VB[4][2];
        #pragma unroll
        for (int kb = 0; kb < 4; ++kb)
            #pragma unroll
            for (int kh = 0; kh < 2; ++kh)
                KB[kb][kh] = *(const bf16x8*)(Kb +
                    ((size_t)(h * NTOK + kt + kb * 16 + li) << 6) + kh * 32 + lg * 8);
        #pragma unroll
        for (int db = 0; db < 4; ++db)
            #pragma unroll
            for (int kh = 0; kh < 2; ++kh)
                VB[db][kh] = *(const bf16x8*)(Vt +
                    ((size_t)(h * 64 + db * 16 + li) << 12) + kt + kh * 32 + lg * 8);

        // ---- scores: q rows (lg*4+p), keys kb*16+li ----
        f32x4 SA[4];
        #pragma unroll
        for (int kb = 0; kb < 4; ++kb) {
            f32x4 z = (f32x4){0.f, 0.f, 0.f, 0.f};
            z = __builtin_amdgcn_mfma_f32_16x16x32_bf16(QA[0], KB[kb][0], z, 0, 0, 0);
            SA[kb] = __builtin_amdgcn_mfma_f32_16x16x32_bf16(QA[1], KB[kb][1], z, 0, 0, 0);
        }

        // ---- online softmax ----
        #pragma unroll
        for (int p = 0; p < 4; ++p) {
            float mx = fmaxf(fmaxf(SA[0][p], SA[1][p]), fmaxf(SA[2][p], SA[3][p]));
            #pragma unroll
            for (int sh = 1; sh < 16; sh <<= 1)
                mx = fmaxf(mx, __shfl_xor(mx, sh));
            const float mo = mrun[p];
            const float mn = fmaxf(mo, mx);
            const float corr = __expf(mo - mn);
            mrun[p] = mn;
            float pv[4], ps = 0.f;
            #pragma unroll
            for (int kb = 0; kb < 4; ++kb) {
                pv[kb] = __expf(SA[kb][p] - mn);
                ps += pv[kb];
            }
            lrun[p] = lrun[p] * corr + ps;   // lane-partial
            #pragma unroll
            for (int db = 0; db < 4; ++db) OA[db][p] *= corr;

            const int ql = lg * 4 + p;   // 0..15
            #pragma unroll
            for (int kb = 0; kb < 4; ++kb) {
                const int kl = kb * 16 + li;
                *(u16*)(Pw + ql * 128 + ((kl * 2) ^ ((ql & 7) << 4))) = f2bf(pv[kb]);
            }
        }

        // ---- PV (per-wave in-order DS: writes complete before reads) ----
        #pragma unroll
        for (int kh = 0; kh < 2; ++kh) {
            const int ql = li;
            bf16x8 PA = *(const bf16x8*)(Pw + ql * 128 +
                            ((kh * 64 + lg * 16) ^ ((ql & 7) << 4)));
            #pragma unroll
            for (int db = 0; db < 4; ++db)
                OA[db] = __builtin_amdgcn_mfma_f32_16x16x32_bf16(
                    PA, VB[db][kh], OA[db], 0, 0, 0);
        }
    }

    // ---- finalize l: one 16-lane reduce per row ----
    #pragma unroll
    for (int p = 0; p < 4; ++p) {
        float ps = lrun[p];
        #pragma unroll
        for (int sh = 1; sh < 16; sh <<= 1) ps += __shfl_xor(ps, sh);
        lrun[p] = ps;
    }

    // ---- cross-wk online-softmax merge (wave-serialized through LDS) ----
    if (wk == 0) {
        #pragma unroll
        for (int p = 0; p < 4; ++p) {
            const int q = lg * 4 + p;
            #pragma unroll
            for (int db = 0; db < 4; ++db)
                Obuf[q * 64 + db * 16 + li] = OA[db][p];
            if (li == 0) { Mbuf[q] = mrun[p]; Lbuf[q] = lrun[p]; }
        }
    }
    #pragma unroll
    for (int wv = 1; wv < 4; ++wv) {
        __syncthreads();
        if (wk == wv) {
            #pragma unroll
            for (int p = 0; p < 4; ++p) {
                const int q = lg * 4 + p;
                const float Mo = Mbuf[q], Lo = Lbuf[q];
                const float mn = fmaxf(Mo, mrun[p]);
                const float a  = __expf(Mo - mn);
                const float b  = __expf(mrun[p] - mn);
                #pragma unroll
                for (int db = 0; db < 4; ++db) {
                    const int idx = q * 64 + db * 16 + li;
                    Obuf[idx] = Obuf[idx] * a + OA[db][p] * b;
                }
                if (li == 0) { Mbuf[q] = mn; Lbuf[q] = Lo * a + lrun[p] * b; }
            }
        }
    }
    __syncthreads();

    // ---- write ctx bf16 (N, E): 256 thr -> 16 q x 64 d ----
    {
        const int q = t >> 4, dc = (t & 15) * 4;
        const float rl = 1.f / Lbuf[q];
        uint2 ov;
        ov.x = (unsigned)f2bf(Obuf[q * 64 + dc + 0] * rl) |
               ((unsigned)f2bf(Obuf[q * 64 + dc + 1] * rl) << 16);
        ov.y = (unsigned)f2bf(Obuf[q * 64 + dc + 2] * rl) |
               ((unsigned)f2bf(Obuf[q * 64 + dc + 3] * rl) << 16);
        *(uint2*)(ctxb + (size_t)(q0 + q) * EMB + h * 64 + dc) = ov;
    }
}

// ---------------------------------------------------------------------------
// LayerNorm(512) + exact GeLU; one WAVE per row (no LDS, no barriers).
// bf16 in (h1b), bf16 out (h2b). 4 rows per 256-thr block.
// ---------------------------------------------------------------------------
__global__ __launch_bounds__(256) void ln_gelu_v2(
    const u16* __restrict__ h1b, const float* __restrict__ g,
    const float* __restrict__ b, u16* __restrict__ h2b)
{
    const int wid = threadIdx.x >> 6, l = threadIdx.x & 63;
    const int row = blockIdx.x * 4 + wid;

    uint4 hv = *(const uint4*)(h1b + (size_t)row * 512 + l * 8);
    const unsigned* hw = (const unsigned*)&hv;
    float v[8];
    #pragma unroll
    for (int j = 0; j < 4; ++j) {
        v[2 * j]     = bf2f((u16)(hw[j] & 0xffff));
        v[2 * j + 1] = bf2f((u16)(hw[j] >> 16));
    }

    float s = 0.f;
    #pragma unroll
    for (int i = 0; i < 8; ++i) s += v[i];
    #pragma unroll
    for (int sh = 1; sh < 64; sh <<= 1) s += __shfl_xor(s, sh);
    const float mu = s * (1.f / 512.f);

    float d[8], vs = 0.f;
    #pragma unroll
    for (int i = 0; i < 8; ++i) { d[i] = v[i] - mu; vs += d[i] * d[i]; }
    #pragma unroll
    for (int sh = 1; sh < 64; sh <<= 1) vs += __shfl_xor(vs, sh);
    const float rstd = rsqrtf(vs * (1.f / 512.f) + 1e-5f);

    float4 g0 = *(const float4*)(g + l * 8);
    float4 g1 = *(const float4*)(g + l * 8 + 4);
    float4 b0 = *(const float4*)(b + l * 8);
    float4 b1 = *(const float4*)(b + l * 8 + 4);
    float gg[8] = {g0.x, g0.y, g0.z, g0.w, g1.x, g1.y, g1.z, g1.w};
    float bb[8] = {b0.x, b0.y, b0.z, b0.w, b1.x, b1.y, b1.z, b1.w};

    uint4 ov;
    unsigned* op = (unsigned*)&ov;
    #pragma unroll
    for (int j = 0; j < 4; ++j) {
        float y0 = d[2 * j] * rstd * gg[2 * j] + bb[2 * j];
        float y1 = d[2 * j + 1] * rstd * gg[2 * j + 1] + bb[2 * j + 1];
        float o0 = 0.5f * y0 * (1.f + erff(y0 * 0.70710678118654752f));
        float o1 = 0.5f * y1 * (1.f + erff(y1 * 0.70710678118654752f));
        op[j] = (unsigned)f2bf(o0) | ((unsigned)f2bf(o1) << 16);
    }
    *(uint4*)(h2b + (size_t)row * 512 + l * 8) = ov;
}

// ---------------------------------------------------------------------------
extern "C" void kernel_launch(void* const* d_in, const int* in_sizes, int n_in,
                              void* d_out, int out_size, void* d_ws, size_t ws_size,
                              hipStream_t stream)
{
    const float* x      = (const float*)d_in[0];
    const float* enc    = (const float*)d_in[1];
    const float* Wqkv_w = (const float*)d_in[2];
    const float* Wqkv_b = (const float*)d_in[3];
    const float* out_w  = (const float*)d_in[4];
    const float* out_b  = (const float*)d_in[5];
    const float* ffn1_w = (const float*)d_in[6];
    const float* ffn1_b = (const float*)d_in[7];
    const float* ln_g   = (const float*)d_in[8];
    const float* ln_b   = (const float*)d_in[9];
    const float* ffn2_w = (const float*)d_in[10];
    const float* ffn2_b = (const float*)d_in[11];
    float* out = (float*)d_out;
    float* ws  = (float*)d_ws;

    // workspace layout (float units)
    u16*   catb = (u16*)(ws);               // 4096x512 bf16
    u16*   wb   = (u16*)(ws + 1048576);     // concat weights bf16
    u16*   Qb   = (u16*)(ws + 1376256);     // 4x4096x64 bf16
    u16*   Kb   = (u16*)(ws + 1900544);
    u16*   Vt   = (u16*)(ws + 2424832);
    u16*   ctxb = (u16*)(ws + 2949120);     // 4096x256 bf16
    u16*   qkvb = (u16*)(ws + 3473408);     // 4096x768 bf16
    u16*   h1b  = (u16*)(ws + 3473408);     // 4096x512 bf16 (reuses qkvb; qkvb dead after qkv_post)
    u16*   xb   = (u16*)(ws + 5570560);     // 4096x256 bf16
    u16*   h2b  = (u16*)(ws + 5570560);     // 4096x512 bf16 (reuses xb after FFN1)

    u16* Wqkvb = wb;
    u16* outwb = wb + 196608;
    u16* ffn1b = wb + 262144;
    u16* ffn2b = wb + 524288;

    // 1. casts
    prep<<<1664, 256, 0, stream>>>((const float4*)Wqkv_w, (const float4*)out_w,
                                   (const float4*)ffn1_w, (const float4*)ffn2_w, wb,
                                   (const float4*)x, xb, catb);
    // 2. QKV projection -> bf16 qkvb
    gemm_bf16_abt<<<dim3(12, 64), 256, 0, stream>>>(xb, Wqkvb, Wqkv_b,
                                                    nullptr, 0, nullptr, qkvb, 768, 256);
    // 3. RoPE + V-transpose (fused; v-transpose via LDS tile)
    qkv_post<<<2304, 256, 0, stream>>>(qkvb, enc, (unsigned*)Qb, (unsigned*)Kb, Vt);
    // 4. attention -> ctxb bf16 (NOTE: h1b aliases qkvb, written later)
    flash_attn_v4<<<dim3(256, NH), 256, 0, stream>>>(Qb, Kb, Vt, ctxb);
    // 5. out_proj -> catb[:, 256:]
    gemm_bf16_abt<<<dim3(4, 64), 256, 0, stream>>>(ctxb, outwb, out_b,
                                                   nullptr, 0, nullptr, catb + 256, 512, 256);
    // 6. FFN1 -> h1b bf16
    gemm_bf16_abt<<<dim3(8, 64), 256, 0, stream>>>(catb, ffn1b, ffn1_b,
                                                   nullptr, 0, nullptr, h1b, 512, 512);
    // 7. LayerNorm + GeLU -> h2b bf16 (wave-per-row)
    ln_gelu_v2<<<1024, 256, 0, stream>>>(h1b, ln_g, ln_b, h2b);
    // 8. FFN2 + residual -> out fp32
    gemm_bf16_abt<<<dim3(4, 64), 256, 0, stream>>>(h2b, ffn2b, ffn2_b,
                                                   x, 256, out, nullptr, 256, 512);
}

// Round 8
// 229.217 us; speedup vs baseline: 1.2248x; 1.2248x over previous
//
#include <hip/hip_runtime.h>
#include <math.h>

// Problem constants (B=1)
#define NTOK 4096
#define EMB  256
#define NH   4
#define HD   64

typedef unsigned short u16;
typedef __attribute__((ext_vector_type(8))) __bf16 bf16x8;
typedef __attribute__((ext_vector_type(4))) float f32x4;

__device__ __forceinline__ u16 f2bf(float f) {
    union { float f; unsigned u; } v; v.f = f;
    unsigned b = v.u;
    b += 0x7FFFu + ((b >> 16) & 1u);     // round-nearest-even
    return (u16)(b >> 16);
}
__device__ __forceinline__ float bf2f(u16 u) {
    union { unsigned u; float f; } v; v.u = ((unsigned)u) << 16;
    return v.f;
}

// ---------------------------------------------------------------------------
// prep = w4cast + xcast fused (grid-partitioned).  (unchanged, verified)
// ---------------------------------------------------------------------------
__global__ __launch_bounds__(256) void prep(
    const float4* __restrict__ w0, const float4* __restrict__ w1,
    const float4* __restrict__ w2, const float4* __restrict__ w3,
    u16* __restrict__ wb,
    const float4* __restrict__ x4, u16* __restrict__ xb, u16* __restrict__ catb)
{
    const int bid = blockIdx.x;
    if (bid < 640) {
        const int f = bid * 256 + threadIdx.x;   // < 163840
        float4 v;
        if      (f <  49152) v = w0[f];
        else if (f <  65536) v = w1[f - 49152];
        else if (f < 131072) v = w2[f - 65536];
        else                 v = w3[f - 131072];
        uint2 o;
        o.x = (unsigned)f2bf(v.x) | ((unsigned)f2bf(v.y) << 16);
        o.y = (unsigned)f2bf(v.z) | ((unsigned)f2bf(v.w) << 16);
        *(uint2*)(wb + (size_t)f * 4) = o;
    } else {
        const int f = (bid - 640) * 256 + threadIdx.x;   // < 262144
        float4 v = x4[f];
        uint2 o;
        o.x = (unsigned)f2bf(v.x) | ((unsigned)f2bf(v.y) << 16);
        o.y = (unsigned)f2bf(v.z) | ((unsigned)f2bf(v.w) << 16);
        *(uint2*)(xb + (size_t)f * 4) = o;
        const int row = f >> 6, c = (f & 63) * 4;
        *(uint2*)(catb + (size_t)row * 512 + c) = o;
    }
}

// ---------------------------------------------------------------------------
// bf16 MFMA GEMM v2: tile 128(M)x64(N), 4 waves, wave owns 32 rows (2x16).
// Software-pipelined: next k-step's 6 fragments prefetched (x2-unrolled loop,
// alternating register buffers) so L2 latency hides under the 8 MFMAs.
// Fragments (HW-verified): A[row=li][k=lg*8+j], B[col=li][k=lg*8+j],
// D[row=lg*4+p][col=li]. K must be a multiple of 64 (256/512 here).
// ---------------------------------------------------------------------------
__global__ __launch_bounds__(256, 4) void gemm_bf16_v2(
    const u16* __restrict__ A,     // [M][K] bf16
    const u16* __restrict__ B,     // [N][K] bf16
    const float* __restrict__ bias,
    const float* __restrict__ resid, int ldr,   // may be null
    float* __restrict__ Cf, u16* __restrict__ Cb, int ldc, int K)
{
    const int t = threadIdx.x, w = t >> 6, l = t & 63;
    const int lg = l >> 4, li = l & 15;
    const int row0 = blockIdx.y * 128 + w * 32;
    const int col0 = blockIdx.x * 64;

    f32x4 acc[2][4];
    #pragma unroll
    for (int m = 0; m < 2; ++m)
        #pragma unroll
        for (int nb = 0; nb < 4; ++nb) acc[m][nb] = (f32x4){0.f, 0.f, 0.f, 0.f};

    const u16* Ap0 = A + (size_t)(row0 + li) * K + lg * 8;
    const u16* Ap1 = Ap0 + (size_t)16 * K;
    const u16* Bp  = B + (size_t)(col0 + li) * K + lg * 8;

    bf16x8 a0c = *(const bf16x8*)(Ap0);
    bf16x8 a1c = *(const bf16x8*)(Ap1);
    bf16x8 b0c = *(const bf16x8*)(Bp);
    bf16x8 b1c = *(const bf16x8*)(Bp + (size_t)16 * K);
    bf16x8 b2c = *(const bf16x8*)(Bp + (size_t)32 * K);
    bf16x8 b3c = *(const bf16x8*)(Bp + (size_t)48 * K);
    bf16x8 a0n, a1n, b0n, b1n, b2n, b3n;

#define GSTEP(a0x,a1x,b0x,b1x,b2x,b3x, a0y,a1y,b0y,b1y,b2y,b3y, KC) do { \
    const int kn_ = ((KC) + 32 < K) ? (KC) + 32 : (KC); \
    a0y = *(const bf16x8*)(Ap0 + kn_); \
    a1y = *(const bf16x8*)(Ap1 + kn_); \
    b0y = *(const bf16x8*)(Bp + kn_); \
    b1y = *(const bf16x8*)(Bp + (size_t)16 * K + kn_); \
    b2y = *(const bf16x8*)(Bp + (size_t)32 * K + kn_); \
    b3y = *(const bf16x8*)(Bp + (size_t)48 * K + kn_); \
    acc[0][0] = __builtin_amdgcn_mfma_f32_16x16x32_bf16(a0x, b0x, acc[0][0], 0, 0, 0); \
    acc[0][1] = __builtin_amdgcn_mfma_f32_16x16x32_bf16(a0x, b1x, acc[0][1], 0, 0, 0); \
    acc[0][2] = __builtin_amdgcn_mfma_f32_16x16x32_bf16(a0x, b2x, acc[0][2], 0, 0, 0); \
    acc[0][3] = __builtin_amdgcn_mfma_f32_16x16x32_bf16(a0x, b3x, acc[0][3], 0, 0, 0); \
    acc[1][0] = __builtin_amdgcn_mfma_f32_16x16x32_bf16(a1x, b0x, acc[1][0], 0, 0, 0); \
    acc[1][1] = __builtin_amdgcn_mfma_f32_16x16x32_bf16(a1x, b1x, acc[1][1], 0, 0, 0); \
    acc[1][2] = __builtin_amdgcn_mfma_f32_16x16x32_bf16(a1x, b2x, acc[1][2], 0, 0, 0); \
    acc[1][3] = __builtin_amdgcn_mfma_f32_16x16x32_bf16(a1x, b3x, acc[1][3], 0, 0, 0); \
} while (0)

    for (int k0 = 0; k0 < K; k0 += 64) {
        GSTEP(a0c,a1c,b0c,b1c,b2c,b3c, a0n,a1n,b0n,b1n,b2n,b3n, k0);
        GSTEP(a0n,a1n,b0n,b1n,b2n,b3n, a0c,a1c,b0c,b1c,b2c,b3c, k0 + 32);
    }
#undef GSTEP

    #pragma unroll
    for (int m = 0; m < 2; ++m)
        #pragma unroll
        for (int nb = 0; nb < 4; ++nb) {
            const int col = col0 + nb * 16 + li;
            const float bs = bias[col];
            #pragma unroll
            for (int p = 0; p < 4; ++p) {
                const int row = row0 + m * 16 + lg * 4 + p;
                float v = acc[m][nb][p] + bs;
                if (resid) v += resid[(size_t)row * ldr + col];
                if (Cf) Cf[(size_t)row * ldc + col] = v;
                else    Cb[(size_t)row * ldc + col] = f2bf(v);
            }
        }
}

// ---------------------------------------------------------------------------
// qkv_post = rope_qk + v_transpose (LDS-tiled) fused.  (unchanged, verified)
// ---------------------------------------------------------------------------
__global__ __launch_bounds__(256) void qkv_post(
    const u16* __restrict__ qkvb, const float* __restrict__ enc,
    unsigned* __restrict__ Qb, unsigned* __restrict__ Kb, u16* __restrict__ Vt)
{
    __shared__ u16 lds[64 * 66];
    const int bid = blockIdx.x;
    if (bid < 2048) {
        const int gid = bid * 256 + threadIdx.x;   // NH*NTOK*32
        const int h   = gid >> 17;
        const int rem = gid & (NTOK * 32 - 1);
        const int n   = rem >> 5;
        const int p   = rem & 31;
        const int d0  = p * 2;

        const u16* base = qkvb + (size_t)n * 768 + h * 192 + d0 * 3;
        const float q0v = bf2f(base[0]), k0 = bf2f(base[1]);
        const float q1  = bf2f(base[3]), k1 = bf2f(base[4]);

        float2 c01 = *(const float2*)(enc + (size_t)n * 64 + d0);
        float2 s01 = *(const float2*)(enc + (size_t)NTOK * 64 + (size_t)n * 64 + d0);

        const float qo0 = (q0v * c01.x - q1 * s01.x) * 0.125f;
        const float qo1 = (q1 * c01.y + q0v * s01.y) * 0.125f;
        const float ko0 = k0 * c01.x - k1 * s01.x;
        const float ko1 = k1 * c01.y + k0 * s01.y;

        const size_t oidx = ((size_t)(h * NTOK + n) << 5) + p;
        Qb[oidx] = (unsigned)f2bf(qo0) | ((unsigned)f2bf(qo1) << 16);
        Kb[oidx] = (unsigned)f2bf(ko0) | ((unsigned)f2bf(ko1) << 16);
    } else {
        const int vb = bid - 2048;
        const int h  = vb >> 6;
        const int nt = vb & 63;
        const int t  = threadIdx.x;

        {
            const int nl = t & 63, dg = t >> 6;   // dg: 0..3 (16 d each)
            const u16* src = qkvb + (size_t)(nt * 64 + nl) * 768 + h * 192 + dg * 48 + 2;
            #pragma unroll
            for (int i = 0; i < 16; ++i)
                lds[(dg * 16 + i) * 66 + nl] = src[3 * i];
        }
        __syncthreads();
        {
            const int d = t >> 2, nc = t & 3;
            __align__(16) u16 us[16];
            #pragma unroll
            for (int i = 0; i < 16; ++i) us[i] = lds[d * 66 + nc * 16 + i];
            u16* dst = Vt + ((size_t)(h * 64 + d) << 12) + nt * 64 + nc * 16;
            *(uint4*)(dst)     = *(uint4*)(us);
            *(uint4*)(dst + 8) = *(uint4*)(us + 8);
        }
    }
}

// ---------------------------------------------------------------------------
// Flash attention v5, bf16 MFMA. q-tile 32/block; 4 waves (256 thr), wave wk
// owns keys [wk*1024,+1024) over ALL 32 q-rows (r4's proven intensity).
// Grid (128,4)=512 blocks -> 2 blocks/CU, 8 waves/CU.
// SOFTWARE PIPELINE: x2-unrolled main loop, alternating K/V register buffers;
// next tile's 16 fragment loads issue FIRST in each body, consumed next body
// -> ~500cy L2 latency hides under QK-MFMA + softmax + PV (~800cy).
// __launch_bounds__(256,2): VGPR cap 256 (need ~240) — no r7-style squeeze.
// ---------------------------------------------------------------------------
__global__ __launch_bounds__(256, 2) void flash_attn_v5(
    const u16* __restrict__ Qb, const u16* __restrict__ Kb,
    const u16* __restrict__ Vt, u16* __restrict__ ctxb)
{
    __shared__ char  Plds[4 * 4096];       // per-wave 32 rows x 128B
    __shared__ float Obuf[32 * 64];
    __shared__ float Mbuf[32], Lbuf[32];

    const int t  = threadIdx.x;
    const int wk = t >> 6;              // 0..3: key-quarter
    const int l  = t & 63;
    const int lg = l >> 4, li = l & 15;
    const int h  = blockIdx.y;
    const int q0 = blockIdx.x * 32;

    char* Pw = Plds + wk * 4096;

    // Q fragments: rows q0 + Mb*16 + li, d = kh*32 + lg*8 + {0..7}
    bf16x8 QA[2][2];
    #pragma unroll
    for (int Mb = 0; Mb < 2; ++Mb)
        #pragma unroll
        for (int kh = 0; kh < 2; ++kh)
            QA[Mb][kh] = *(const bf16x8*)(Qb +
                ((size_t)(h * NTOK + q0 + Mb * 16 + li) << 6) + kh * 32 + lg * 8);

    f32x4 OA[2][4];
    float mrun[2][4], lrun[2][4];   // lrun lane-partial until the end
    #pragma unroll
    for (int Mb = 0; Mb < 2; ++Mb) {
        #pragma unroll
        for (int p = 0; p < 4; ++p) { mrun[Mb][p] = -1e30f; lrun[Mb][p] = 0.f; }
        #pragma unroll
        for (int db = 0; db < 4; ++db) OA[Mb][db] = (f32x4){0.f, 0.f, 0.f, 0.f};
    }

    // double-buffered K/V fragment sets
    bf16x8 K0f[4][2], V0f[4][2], K1f[4][2], V1f[4][2];

    // preload tile 0
    {
        const int kt0 = wk << 10;
        #pragma unroll
        for (int kb = 0; kb < 4; ++kb)
            #pragma unroll
            for (int kh = 0; kh < 2; ++kh) {
                K0f[kb][kh] = *(const bf16x8*)(Kb +
                    ((size_t)(h * NTOK + kt0 + kb * 16 + li) << 6) + kh * 32 + lg * 8);
                V0f[kb][kh] = *(const bf16x8*)(Vt +
                    ((size_t)(h * 64 + kb * 16 + li) << 12) + kt0 + kh * 32 + lg * 8);
            }
    }

#define FITER(KC, VC, KN, VN, IT) do { \
    const int itn_ = ((IT) < 15) ? (IT) + 1 : (IT); \
    const int ktn_ = (wk << 10) + (itn_ << 6); \
    _Pragma("unroll") \
    for (int kb = 0; kb < 4; ++kb) { \
        _Pragma("unroll") \
        for (int kh = 0; kh < 2; ++kh) { \
            KN[kb][kh] = *(const bf16x8*)(Kb + \
                ((size_t)(h * NTOK + ktn_ + kb * 16 + li) << 6) + kh * 32 + lg * 8); \
            VN[kb][kh] = *(const bf16x8*)(Vt + \
                ((size_t)(h * 64 + kb * 16 + li) << 12) + ktn_ + kh * 32 + lg * 8); \
        } \
    } \
    f32x4 SA_[2][4]; \
    _Pragma("unroll") \
    for (int Mb = 0; Mb < 2; ++Mb) { \
        _Pragma("unroll") \
        for (int kb = 0; kb < 4; ++kb) { \
            f32x4 z_ = (f32x4){0.f, 0.f, 0.f, 0.f}; \
            z_ = __builtin_amdgcn_mfma_f32_16x16x32_bf16(QA[Mb][0], KC[kb][0], z_, 0, 0, 0); \
            SA_[Mb][kb] = __builtin_amdgcn_mfma_f32_16x16x32_bf16(QA[Mb][1], KC[kb][1], z_, 0, 0, 0); \
        } \
    } \
    _Pragma("unroll") \
    for (int Mb = 0; Mb < 2; ++Mb) { \
        _Pragma("unroll") \
        for (int p = 0; p < 4; ++p) { \
            float mx_ = fmaxf(fmaxf(SA_[Mb][0][p], SA_[Mb][1][p]), \
                              fmaxf(SA_[Mb][2][p], SA_[Mb][3][p])); \
            _Pragma("unroll") \
            for (int sh = 1; sh < 16; sh <<= 1) mx_ = fmaxf(mx_, __shfl_xor(mx_, sh)); \
            const float mo_ = mrun[Mb][p]; \
            const float mn_ = fmaxf(mo_, mx_); \
            const float corr_ = __expf(mo_ - mn_); \
            mrun[Mb][p] = mn_; \
            float pe0_ = __expf(SA_[Mb][0][p] - mn_); \
            float pe1_ = __expf(SA_[Mb][1][p] - mn_); \
            float pe2_ = __expf(SA_[Mb][2][p] - mn_); \
            float pe3_ = __expf(SA_[Mb][3][p] - mn_); \
            lrun[Mb][p] = lrun[Mb][p] * corr_ + (pe0_ + pe1_ + pe2_ + pe3_); \
            _Pragma("unroll") \
            for (int db = 0; db < 4; ++db) OA[Mb][db][p] *= corr_; \
            const int ql_ = Mb * 16 + lg * 4 + p; \
            *(u16*)(Pw + ql_ * 128 + (((0 * 16 + li) * 2) ^ ((ql_ & 7) << 4))) = f2bf(pe0_); \
            *(u16*)(Pw + ql_ * 128 + (((1 * 16 + li) * 2) ^ ((ql_ & 7) << 4))) = f2bf(pe1_); \
            *(u16*)(Pw + ql_ * 128 + (((2 * 16 + li) * 2) ^ ((ql_ & 7) << 4))) = f2bf(pe2_); \
            *(u16*)(Pw + ql_ * 128 + (((3 * 16 + li) * 2) ^ ((ql_ & 7) << 4))) = f2bf(pe3_); \
        } \
    } \
    _Pragma("unroll") \
    for (int Mb = 0; Mb < 2; ++Mb) { \
        _Pragma("unroll") \
        for (int kh = 0; kh < 2; ++kh) { \
            const int ql_ = Mb * 16 + li; \
            bf16x8 PA_ = *(const bf16x8*)(Pw + ql_ * 128 + \
                            ((kh * 64 + lg * 16) ^ ((ql_ & 7) << 4))); \
            _Pragma("unroll") \
            for (int db = 0; db < 4; ++db) \
                OA[Mb][db] = __builtin_amdgcn_mfma_f32_16x16x32_bf16( \
                    PA_, VC[db][kh], OA[Mb][db], 0, 0, 0); \
        } \
    } \
} while (0)

    for (int it = 0; it < 16; it += 2) {
        FITER(K0f, V0f, K1f, V1f, it);
        FITER(K1f, V1f, K0f, V0f, it + 1);
    }
#undef FITER

    // ---- finalize l: one 16-lane reduce per row ----
    #pragma unroll
    for (int Mb = 0; Mb < 2; ++Mb)
        #pragma unroll
        for (int p = 0; p < 4; ++p) {
            float ps = lrun[Mb][p];
            #pragma unroll
            for (int sh = 1; sh < 16; sh <<= 1) ps += __shfl_xor(ps, sh);
            lrun[Mb][p] = ps;
        }

    // ---- cross-wk online-softmax merge (wave-serialized through LDS) ----
    if (wk == 0) {
        #pragma unroll
        for (int Mb = 0; Mb < 2; ++Mb)
            #pragma unroll
            for (int p = 0; p < 4; ++p) {
                const int q = Mb * 16 + lg * 4 + p;
                #pragma unroll
                for (int db = 0; db < 4; ++db)
                    Obuf[q * 64 + db * 16 + li] = OA[Mb][db][p];
                if (li == 0) { Mbuf[q] = mrun[Mb][p]; Lbuf[q] = lrun[Mb][p]; }
            }
    }
    #pragma unroll
    for (int wv = 1; wv < 4; ++wv) {
        __syncthreads();
        if (wk == wv) {
            #pragma unroll
            for (int Mb = 0; Mb < 2; ++Mb)
                #pragma unroll
                for (int p = 0; p < 4; ++p) {
                    const int q = Mb * 16 + lg * 4 + p;
                    const float Mo = Mbuf[q], Lo = Lbuf[q];
                    const float mn = fmaxf(Mo, mrun[Mb][p]);
                    const float a  = __expf(Mo - mn);
                    const float b  = __expf(mrun[Mb][p] - mn);
                    #pragma unroll
                    for (int db = 0; db < 4; ++db) {
                        const int idx = q * 64 + db * 16 + li;
                        Obuf[idx] = Obuf[idx] * a + OA[Mb][db][p] * b;
                    }
                    if (li == 0) { Mbuf[q] = mn; Lbuf[q] = Lo * a + lrun[Mb][p] * b; }
                }
        }
    }
    __syncthreads();

    // ---- write ctx bf16 (N, E): 256 thr -> 32 q x 64 d (8 bf16/thr) ----
    {
        const int q = t >> 3, dc = (t & 7) * 8;
        const float rl = 1.f / Lbuf[q];
        uint4 ov;
        unsigned* op = (unsigned*)&ov;
        #pragma unroll
        for (int i = 0; i < 8; i += 2)
            op[i >> 1] = (unsigned)f2bf(Obuf[q * 64 + dc + i] * rl) |
                         ((unsigned)f2bf(Obuf[q * 64 + dc + i + 1] * rl) << 16);
        *(uint4*)(ctxb + (size_t)(q0 + q) * EMB + h * 64 + dc) = ov;
    }
}

// ---------------------------------------------------------------------------
// LayerNorm(512) + exact GeLU; one WAVE per row.  (unchanged, verified)
// ---------------------------------------------------------------------------
__global__ __launch_bounds__(256) void ln_gelu_v2(
    const u16* __restrict__ h1b, const float* __restrict__ g,
    const float* __restrict__ b, u16* __restrict__ h2b)
{
    const int wid = threadIdx.x >> 6, l = threadIdx.x & 63;
    const int row = blockIdx.x * 4 + wid;

    uint4 hv = *(const uint4*)(h1b + (size_t)row * 512 + l * 8);
    const unsigned* hw = (const unsigned*)&hv;
    float v[8];
    #pragma unroll
    for (int j = 0; j < 4; ++j) {
        v[2 * j]     = bf2f((u16)(hw[j] & 0xffff));
        v[2 * j + 1] = bf2f((u16)(hw[j] >> 16));
    }

    float s = 0.f;
    #pragma unroll
    for (int i = 0; i < 8; ++i) s += v[i];
    #pragma unroll
    for (int sh = 1; sh < 64; sh <<= 1) s += __shfl_xor(s, sh);
    const float mu = s * (1.f / 512.f);

    float d[8], vs = 0.f;
    #pragma unroll
    for (int i = 0; i < 8; ++i) { d[i] = v[i] - mu; vs += d[i] * d[i]; }
    #pragma unroll
    for (int sh = 1; sh < 64; sh <<= 1) vs += __shfl_xor(vs, sh);
    const float rstd = rsqrtf(vs * (1.f / 512.f) + 1e-5f);

    float4 g0 = *(const float4*)(g + l * 8);
    float4 g1 = *(const float4*)(g + l * 8 + 4);
    float4 b0 = *(const float4*)(b + l * 8);
    float4 b1 = *(const float4*)(b + l * 8 + 4);
    float gg[8] = {g0.x, g0.y, g0.z, g0.w, g1.x, g1.y, g1.z, g1.w};
    float bb[8] = {b0.x, b0.y, b0.z, b0.w, b1.x, b1.y, b1.z, b1.w};

    uint4 ov;
    unsigned* op = (unsigned*)&ov;
    #pragma unroll
    for (int j = 0; j < 4; ++j) {
        float y0 = d[2 * j] * rstd * gg[2 * j] + bb[2 * j];
        float y1 = d[2 * j + 1] * rstd * gg[2 * j + 1] + bb[2 * j + 1];
        float o0 = 0.5f * y0 * (1.f + erff(y0 * 0.70710678118654752f));
        float o1 = 0.5f * y1 * (1.f + erff(y1 * 0.70710678118654752f));
        op[j] = (unsigned)f2bf(o0) | ((unsigned)f2bf(o1) << 16);
    }
    *(uint4*)(h2b + (size_t)row * 512 + l * 8) = ov;
}

// ---------------------------------------------------------------------------
extern "C" void kernel_launch(void* const* d_in, const int* in_sizes, int n_in,
                              void* d_out, int out_size, void* d_ws, size_t ws_size,
                              hipStream_t stream)
{
    const float* x      = (const float*)d_in[0];
    const float* enc    = (const float*)d_in[1];
    const float* Wqkv_w = (const float*)d_in[2];
    const float* Wqkv_b = (const float*)d_in[3];
    const float* out_w  = (const float*)d_in[4];
    const float* out_b  = (const float*)d_in[5];
    const float* ffn1_w = (const float*)d_in[6];
    const float* ffn1_b = (const float*)d_in[7];
    const float* ln_g   = (const float*)d_in[8];
    const float* ln_b   = (const float*)d_in[9];
    const float* ffn2_w = (const float*)d_in[10];
    const float* ffn2_b = (const float*)d_in[11];
    float* out = (float*)d_out;
    float* ws  = (float*)d_ws;

    // workspace layout (float units)
    u16*   catb = (u16*)(ws);               // 4096x512 bf16
    u16*   wb   = (u16*)(ws + 1048576);     // concat weights bf16
    u16*   Qb   = (u16*)(ws + 1376256);     // 4x4096x64 bf16
    u16*   Kb   = (u16*)(ws + 1900544);
    u16*   Vt   = (u16*)(ws + 2424832);
    u16*   ctxb = (u16*)(ws + 2949120);     // 4096x256 bf16
    u16*   qkvb = (u16*)(ws + 3473408);     // 4096x768 bf16
    u16*   h1b  = (u16*)(ws + 3473408);     // 4096x512 bf16 (reuses qkvb)
    u16*   xb   = (u16*)(ws + 5570560);     // 4096x256 bf16
    u16*   h2b  = (u16*)(ws + 5570560);     // 4096x512 bf16 (reuses xb)

    u16* Wqkvb = wb;
    u16* outwb = wb + 196608;
    u16* ffn1b = wb + 262144;
    u16* ffn2b = wb + 524288;

    // 1. casts
    prep<<<1664, 256, 0, stream>>>((const float4*)Wqkv_w, (const float4*)out_w,
                                   (const float4*)ffn1_w, (const float4*)ffn2_w, wb,
                                   (const float4*)x, xb, catb);
    // 2. QKV projection -> bf16 qkvb  (M=4096 -> 32 row-tiles of 128)
    gemm_bf16_v2<<<dim3(12, 32), 256, 0, stream>>>(xb, Wqkvb, Wqkv_b,
                                                   nullptr, 0, nullptr, qkvb, 768, 256);
    // 3. RoPE + V-transpose (fused)
    qkv_post<<<2304, 256, 0, stream>>>(qkvb, enc, (unsigned*)Qb, (unsigned*)Kb, Vt);
    // 4. attention -> ctxb bf16
    flash_attn_v5<<<dim3(128, NH), 256, 0, stream>>>(Qb, Kb, Vt, ctxb);
    // 5. out_proj -> catb[:, 256:]
    gemm_bf16_v2<<<dim3(4, 32), 256, 0, stream>>>(ctxb, outwb, out_b,
                                                  nullptr, 0, nullptr, catb + 256, 512, 256);
    // 6. FFN1 -> h1b bf16
    gemm_bf16_v2<<<dim3(8, 32), 256, 0, stream>>>(catb, ffn1b, ffn1_b,
                                                  nullptr, 0, nullptr, h1b, 512, 512);
    // 7. LayerNorm + GeLU -> h2b bf16 (wave-per-row)
    ln_gelu_v2<<<1024, 256, 0, stream>>>(h1b, ln_g, ln_b, h2b);
    // 8. FFN2 + residual -> out fp32
    gemm_bf16_v2<<<dim3(4, 32), 256, 0, stream>>>(h2b, ffn2b, ffn2_b,
                                                  x, 256, out, nullptr, 256, 512);
}